// Round 4
// baseline (365.202 us; speedup 1.0000x reference)
//
#include <hip/hip_runtime.h>
#include <math.h>

#define N_NODES 50000
#define N_EDGES 800000
#define NB1 196  // ceil(50000/256)

__device__ __forceinline__ float readlane_f(float v, int lane) {
    return __int_as_float(__builtin_amdgcn_readlane(__float_as_int(v), lane));
}

// Derived weights:
//   Wcat[i][m]    = sum_k W2[i][64+k]*We[k][m]   (edge-feat path, m<64)
//   Wcat[i][64+m] = W2[i*96+m]                   (z-src path)
//   wca[m] = sum_k Wa[64+k]*We[k][m]
__global__ void kw_kernel(const float* __restrict__ W2, const float* __restrict__ We,
                          const float* __restrict__ Wa,
                          float* __restrict__ Wcat, float* __restrict__ wca) {
    int t = blockIdx.x * blockDim.x + threadIdx.x;
    if (t < 64 * 64) {
        int i = t >> 6, m = t & 63;
        float acc = 0.f;
        #pragma unroll
        for (int k = 0; k < 32; ++k) acc += W2[i * 96 + 64 + k] * We[k * 64 + m];
        Wcat[i * 128 + m] = acc;
        Wcat[i * 128 + 64 + m] = W2[i * 96 + m];
    }
    if (t < 64) {
        float acc = 0.f;
        #pragma unroll
        for (int k = 0; k < 32; ++k) acc += Wa[64 + k] * We[k * 64 + t];
        wca[t] = acc;
    }
}

// Per-node: z = h@Wn^T, asrc = z.Wa[0:64], adst = z.Wa[96:160]
__global__ __launch_bounds__(256) void node_kernel(
    const float* __restrict__ h, const float* __restrict__ Wn,
    const float* __restrict__ Wa,
    float* __restrict__ z, float* __restrict__ asrc, float* __restrict__ adst)
{
    __shared__ float sWn[64 * 132];   // stride 132: 16B-aligned rows
    __shared__ float sh[4][128];
    int t = threadIdx.x;
    for (int idx = t; idx < 64 * 128; idx += 256) {
        int r = idx >> 7, c = idx & 127;
        sWn[r * 132 + c] = Wn[idx];
    }
    int w = t >> 6, l = t & 63;
    float wa0 = Wa[l], wa2 = Wa[96 + l];
    __syncthreads();
    for (int n0 = blockIdx.x * 4; n0 < N_NODES; n0 += gridDim.x * 4) {
        if (t < 128) {
            int nn = t >> 5, c4 = t & 31;
            int n = n0 + nn;
            if (n < N_NODES)
                ((float4*)&sh[nn][0])[c4] = ((const float4*)h)[(size_t)n * 32 + c4];
        }
        __syncthreads();
        int n = n0 + w;
        if (n < N_NODES) {
            float acc = 0.f;
            #pragma unroll
            for (int q = 0; q < 32; ++q) {
                float4 wv = *(const float4*)&sWn[l * 132 + q * 4];
                float4 hv = *(const float4*)&sh[w][q * 4];
                acc += wv.x * hv.x + wv.y * hv.y + wv.z * hv.z + wv.w * hv.w;
            }
            z[(size_t)n * 64 + l] = acc;
            float p0 = acc * wa0, p1 = acc * wa2;
            #pragma unroll
            for (int off = 32; off; off >>= 1) {
                p0 += __shfl_xor(p0, off);
                p1 += __shfl_xor(p1, off);
            }
            if (l == 0) { asrc[n] = p0; adst[n] = p1; }
        }
        __syncthreads();
    }
}

// ---- CSR build ----
__global__ void hist_kernel(const int* __restrict__ dst, int* __restrict__ degi) {
    int e = blockIdx.x * 256 + threadIdx.x;
    if (e < N_EDGES) atomicAdd(&degi[dst[e]], 1);
}

__global__ __launch_bounds__(256) void scan1_kernel(const int* __restrict__ degi,
                                                    int* __restrict__ partial) {
    int t = threadIdx.x, i = blockIdx.x * 256 + t;
    int d = (i < N_NODES) ? degi[i] : 0;
    #pragma unroll
    for (int off = 32; off; off >>= 1) d += __shfl_down(d, off);
    __shared__ int wsum[4];
    if ((t & 63) == 0) wsum[t >> 6] = d;
    __syncthreads();
    if (t == 0) partial[blockIdx.x] = wsum[0] + wsum[1] + wsum[2] + wsum[3];
}

__global__ __launch_bounds__(256) void scan2_kernel(int* __restrict__ partial) {
    __shared__ int s[256];
    int t = threadIdx.x;
    int v = (t < NB1) ? partial[t] : 0;
    s[t] = v; __syncthreads();
    for (int off = 1; off < 256; off <<= 1) {
        int x = (t >= off) ? s[t - off] : 0;
        __syncthreads();
        s[t] += x;
        __syncthreads();
    }
    if (t < NB1) partial[t] = s[t] - v;   // exclusive, in place
}

__global__ __launch_bounds__(256) void scan3_kernel(const int* __restrict__ degi,
                                                    const int* __restrict__ partial,
                                                    int* __restrict__ start,
                                                    int* __restrict__ cursor) {
    __shared__ int s[256];
    int t = threadIdx.x, i = blockIdx.x * 256 + t;
    int d = (i < N_NODES) ? degi[i] : 0;
    s[t] = d; __syncthreads();
    for (int off = 1; off < 256; off <<= 1) {
        int x = (t >= off) ? s[t - off] : 0;
        __syncthreads();
        s[t] += x;
        __syncthreads();
    }
    if (i < N_NODES) {
        int st = partial[blockIdx.x] + s[t] - d;
        start[i] = st;
        cursor[i] = st;
    }
}

__global__ void scatter_kernel(const int* __restrict__ src, const int* __restrict__ dst,
                               int* __restrict__ cursor, int2* __restrict__ edata) {
    int e = blockIdx.x * 256 + threadIdx.x;
    if (e < N_EDGES) {
        int d = dst[e];
        int pos = atomicAdd(&cursor[d], 1);
        edata[pos] = make_int2(e, src[e]);
    }
}

// ---- aggregation: one wave per node; register-resident metadata, scalar-addressed
//      row loads (no vector address dependency), 16-deep MLP ----
__global__ __launch_bounds__(256, 4) void agg_kernel(
    const float* __restrict__ edge_feat, const int2* __restrict__ edata,
    const int* __restrict__ start, const int* __restrict__ degi,
    const float* __restrict__ asrc, const float* __restrict__ adst,
    const float* __restrict__ z, const float* __restrict__ wca,
    const float* __restrict__ Wcat, float* __restrict__ out)
{
    __shared__ float stu[4][132];
    int t = threadIdx.x, w = t >> 6, l = t & 63;
    float wcal = wca[l];
    int d    = blockIdx.x * 4 + w;               // grid exact: 12500*4 = 50000
    int base = __builtin_amdgcn_readfirstlane(start[d]);
    int deg  = __builtin_amdgcn_readfirstlane(degi[d]);
    float ad = adst[d];
    float tm = 0.f, um = 0.f, den = 0.f;

    for (int c0 = 0; c0 < deg; c0 += 64) {
        int cc = min(deg - c0, 64);              // wave-uniform
        // preload metadata for up to 64 edges into lane registers
        int exi = 0, eyi = 0; float axl = 0.f;
        if (l < cc) {
            int2 es = edata[base + c0 + l];
            exi = es.x; eyi = es.y;
            axl = asrc[es.y];
        }
        for (int c = 0; c < cc; c += 16) {
            int cnt = cc - c;                    // wave-uniform guard
            float EF0=0,EF1=0,EF2=0,EF3=0,EF4=0,EF5=0,EF6=0,EF7=0,
                  EF8=0,EF9=0,EF10=0,EF11=0,EF12=0,EF13=0,EF14=0,EF15=0;
            float ZL0=0,ZL1=0,ZL2=0,ZL3=0,ZL4=0,ZL5=0,ZL6=0,ZL7=0,
                  ZL8=0,ZL9=0,ZL10=0,ZL11=0,ZL12=0,ZL13=0,ZL14=0,ZL15=0;

            // Phase 1: scalar indices via readlane; issue all row loads
            #define LOADJ(J, EF, ZL)                                        \
                if (J < cnt) {                                              \
                    int sx = __builtin_amdgcn_readlane(exi, c + J);         \
                    int sy = __builtin_amdgcn_readlane(eyi, c + J);         \
                    EF = edge_feat[(size_t)sx * 64 + l];                    \
                    ZL = z[(size_t)sy * 64 + l];                            \
                }
            LOADJ(0,EF0,ZL0)   LOADJ(1,EF1,ZL1)   LOADJ(2,EF2,ZL2)
            LOADJ(3,EF3,ZL3)   LOADJ(4,EF4,ZL4)   LOADJ(5,EF5,ZL5)
            LOADJ(6,EF6,ZL6)   LOADJ(7,EF7,ZL7)   LOADJ(8,EF8,ZL8)
            LOADJ(9,EF9,ZL9)   LOADJ(10,EF10,ZL10) LOADJ(11,EF11,ZL11)
            LOADJ(12,EF12,ZL12) LOADJ(13,EF13,ZL13) LOADJ(14,EF14,ZL14)
            LOADJ(15,EF15,ZL15)
            #undef LOADJ

            // Phase 2: independent dot/exp/accumulate chains
            #define COMPJ(J, EF, ZL)                                        \
                if (J < cnt) {                                              \
                    float p = EF * wcal;                                    \
                    p += __shfl_xor(p, 32); p += __shfl_xor(p, 16);         \
                    p += __shfl_xor(p, 8);  p += __shfl_xor(p, 4);          \
                    p += __shfl_xor(p, 2);  p += __shfl_xor(p, 1);          \
                    float a = readlane_f(axl, c + J) + p + ad;              \
                    float s = a > 0.f ? a : 0.01f * a;                      \
                    float ex = __expf(s);                                   \
                    tm += ex * EF; um += ex * ZL; den += ex;                \
                }
            COMPJ(0,EF0,ZL0)   COMPJ(1,EF1,ZL1)   COMPJ(2,EF2,ZL2)
            COMPJ(3,EF3,ZL3)   COMPJ(4,EF4,ZL4)   COMPJ(5,EF5,ZL5)
            COMPJ(6,EF6,ZL6)   COMPJ(7,EF7,ZL7)   COMPJ(8,EF8,ZL8)
            COMPJ(9,EF9,ZL9)   COMPJ(10,EF10,ZL10) COMPJ(11,EF11,ZL11)
            COMPJ(12,EF12,ZL12) COMPJ(13,EF13,ZL13) COMPJ(14,EF14,ZL14)
            COMPJ(15,EF15,ZL15)
            #undef COMPJ
        }
    }

    // per-node epilogue: out = ([t,u] @ Wcat^T) / den
    stu[w][l] = tm;
    stu[w][64 + l] = um;
    if (deg > 0) {
        float acc = 0.f;
        #pragma unroll
        for (int q = 0; q < 32; ++q) {
            float4 wv = *(const float4*)&Wcat[l * 128 + q * 4];
            float4 tv = *(const float4*)&stu[w][q * 4];
            acc += wv.x * tv.x + wv.y * tv.y + wv.z * tv.z + wv.w * tv.w;
        }
        out[(size_t)d * 64 + l] = acc / den;
    } else {
        out[(size_t)d * 64 + l] = z[(size_t)d * 64 + l];
    }
}

extern "C" void kernel_launch(void* const* d_in, const int* in_sizes, int n_in,
                              void* d_out, int out_size, void* d_ws, size_t ws_size,
                              hipStream_t stream) {
    const float* h         = (const float*)d_in[0];
    const float* edge_feat = (const float*)d_in[1];
    const int*   src       = (const int*)d_in[2];
    const int*   dst       = (const int*)d_in[3];
    const float* Wn        = (const float*)d_in[4];
    const float* We        = (const float*)d_in[5];
    const float* Wa        = (const float*)d_in[6];
    const float* W2        = (const float*)d_in[7];
    float* out = (float*)d_out;

    char* p = (char*)d_ws;
    float* z      = (float*)p; p += (size_t)N_NODES * 64 * 4;
    float* asrc   = (float*)p; p += (size_t)N_NODES * 4;
    float* adst   = (float*)p; p += (size_t)N_NODES * 4;
    int*   degi   = (int*)p;   p += (size_t)N_NODES * 4;
    int*   start  = (int*)p;   p += (size_t)N_NODES * 4;
    int*   cursor = (int*)p;   p += (size_t)N_NODES * 4;
    int*   partial= (int*)p;   p += (size_t)256 * 4;
    int2*  edata  = (int2*)p;  p += (size_t)N_EDGES * 8;
    float* Wcat   = (float*)p; p += (size_t)64 * 128 * 4;
    float* wca    = (float*)p; p += (size_t)64 * 4;

    hipMemsetAsync(degi, 0, (size_t)N_NODES * 4, stream);

    kw_kernel<<<16, 256, 0, stream>>>(W2, We, Wa, Wcat, wca);
    node_kernel<<<1024, 256, 0, stream>>>(h, Wn, Wa, z, asrc, adst);
    hist_kernel<<<(N_EDGES + 255) / 256, 256, 0, stream>>>(dst, degi);
    scan1_kernel<<<NB1, 256, 0, stream>>>(degi, partial);
    scan2_kernel<<<1, 256, 0, stream>>>(partial);
    scan3_kernel<<<NB1, 256, 0, stream>>>(degi, partial, start, cursor);
    scatter_kernel<<<(N_EDGES + 255) / 256, 256, 0, stream>>>(src, dst, cursor, edata);
    agg_kernel<<<N_NODES / 4, 256, 0, stream>>>(edge_feat, edata, start, degi,
                                                asrc, adst, z, wca, Wcat, out);
}

// Round 5
// 349.684 us; speedup vs baseline: 1.0444x; 1.0444x over previous
//
#include <hip/hip_runtime.h>
#include <math.h>

#define N_NODES 50000
#define N_EDGES 800000
#define NB1 196  // ceil(50000/256)

// Derived weights:
//   Wcat[i][m]    = sum_k W2[i][64+k]*We[k][m]   (edge-feat path, m<64)
//   Wcat[i][64+m] = W2[i*96+m]                   (z-src path)
//   wca[m] = sum_k Wa[64+k]*We[k][m]
__global__ void kw_kernel(const float* __restrict__ W2, const float* __restrict__ We,
                          const float* __restrict__ Wa,
                          float* __restrict__ Wcat, float* __restrict__ wca) {
    int t = blockIdx.x * blockDim.x + threadIdx.x;
    if (t < 64 * 64) {
        int i = t >> 6, m = t & 63;
        float acc = 0.f;
        #pragma unroll
        for (int k = 0; k < 32; ++k) acc += W2[i * 96 + 64 + k] * We[k * 64 + m];
        Wcat[i * 128 + m] = acc;
        Wcat[i * 128 + 64 + m] = W2[i * 96 + m];
    }
    if (t < 64) {
        float acc = 0.f;
        #pragma unroll
        for (int k = 0; k < 32; ++k) acc += Wa[64 + k] * We[k * 64 + t];
        wca[t] = acc;
    }
}

// Per-node: z = h@Wn^T, asrc = z.Wa[0:64], adst = z.Wa[96:160]
__global__ __launch_bounds__(256) void node_kernel(
    const float* __restrict__ h, const float* __restrict__ Wn,
    const float* __restrict__ Wa,
    float* __restrict__ z, float* __restrict__ asrc, float* __restrict__ adst)
{
    __shared__ float sWn[64 * 132];   // stride 132: 16B-aligned rows
    __shared__ float sh[4][128];
    int t = threadIdx.x;
    for (int idx = t; idx < 64 * 128; idx += 256) {
        int r = idx >> 7, c = idx & 127;
        sWn[r * 132 + c] = Wn[idx];
    }
    int w = t >> 6, l = t & 63;
    float wa0 = Wa[l], wa2 = Wa[96 + l];
    __syncthreads();
    for (int n0 = blockIdx.x * 4; n0 < N_NODES; n0 += gridDim.x * 4) {
        if (t < 128) {
            int nn = t >> 5, c4 = t & 31;
            int n = n0 + nn;
            if (n < N_NODES)
                ((float4*)&sh[nn][0])[c4] = ((const float4*)h)[(size_t)n * 32 + c4];
        }
        __syncthreads();
        int n = n0 + w;
        if (n < N_NODES) {
            float acc = 0.f;
            #pragma unroll
            for (int q = 0; q < 32; ++q) {
                float4 wv = *(const float4*)&sWn[l * 132 + q * 4];
                float4 hv = *(const float4*)&sh[w][q * 4];
                acc += wv.x * hv.x + wv.y * hv.y + wv.z * hv.z + wv.w * hv.w;
            }
            z[(size_t)n * 64 + l] = acc;
            float p0 = acc * wa0, p1 = acc * wa2;
            #pragma unroll
            for (int off = 32; off; off >>= 1) {
                p0 += __shfl_xor(p0, off);
                p1 += __shfl_xor(p1, off);
            }
            if (l == 0) { asrc[n] = p0; adst[n] = p1; }
        }
        __syncthreads();
    }
}

// ---- CSR build ----
__global__ void hist_kernel(const int* __restrict__ dst, int* __restrict__ degi) {
    int e = blockIdx.x * 256 + threadIdx.x;
    if (e < N_EDGES) atomicAdd(&degi[dst[e]], 1);
}

__global__ __launch_bounds__(256) void scan1_kernel(const int* __restrict__ degi,
                                                    int* __restrict__ partial) {
    int t = threadIdx.x, i = blockIdx.x * 256 + t;
    int d = (i < N_NODES) ? degi[i] : 0;
    #pragma unroll
    for (int off = 32; off; off >>= 1) d += __shfl_down(d, off);
    __shared__ int wsum[4];
    if ((t & 63) == 0) wsum[t >> 6] = d;
    __syncthreads();
    if (t == 0) partial[blockIdx.x] = wsum[0] + wsum[1] + wsum[2] + wsum[3];
}

__global__ __launch_bounds__(256) void scan2_kernel(int* __restrict__ partial) {
    __shared__ int s[256];
    int t = threadIdx.x;
    int v = (t < NB1) ? partial[t] : 0;
    s[t] = v; __syncthreads();
    for (int off = 1; off < 256; off <<= 1) {
        int x = (t >= off) ? s[t - off] : 0;
        __syncthreads();
        s[t] += x;
        __syncthreads();
    }
    if (t < NB1) partial[t] = s[t] - v;   // exclusive, in place
}

__global__ __launch_bounds__(256) void scan3_kernel(const int* __restrict__ degi,
                                                    const int* __restrict__ partial,
                                                    int* __restrict__ start,
                                                    int* __restrict__ cursor) {
    __shared__ int s[256];
    int t = threadIdx.x, i = blockIdx.x * 256 + t;
    int d = (i < N_NODES) ? degi[i] : 0;
    s[t] = d; __syncthreads();
    for (int off = 1; off < 256; off <<= 1) {
        int x = (t >= off) ? s[t - off] : 0;
        __syncthreads();
        s[t] += x;
        __syncthreads();
    }
    if (i < N_NODES) {
        int st = partial[blockIdx.x] + s[t] - d;
        start[i] = st;
        cursor[i] = st;
    }
}

__global__ void scatter_kernel(const int* __restrict__ src, const int* __restrict__ dst,
                               int* __restrict__ cursor, int2* __restrict__ edata) {
    int e = blockIdx.x * 256 + threadIdx.x;
    if (e < N_EDGES) {
        int d = dst[e];
        int pos = atomicAdd(&cursor[d], 1);
        edata[pos] = make_int2(e, src[e]);
    }
}

// ---- aggregation: one wave per node; 16 lanes per edge, 4 edges per load instr ----
__global__ __launch_bounds__(256, 4) void agg_kernel(
    const float* __restrict__ edge_feat, const int2* __restrict__ edata,
    const int* __restrict__ start, const int* __restrict__ degi,
    const float* __restrict__ asrc, const float* __restrict__ adst,
    const float* __restrict__ z, const float* __restrict__ wca,
    const float* __restrict__ Wcat, float* __restrict__ out)
{
    __shared__ float stu[4][132];
    int t = threadIdx.x, w = t >> 6, l = t & 63;
    int g = l >> 4;        // edge-slot group 0..3
    int q = l & 15;        // quad within row
    float4 wca4 = ((const float4*)wca)[q];
    int d    = blockIdx.x * 4 + w;               // grid exact: 12500*4 = 50000
    int base = __builtin_amdgcn_readfirstlane(start[d]);
    int deg  = __builtin_amdgcn_readfirstlane(degi[d]);
    float ad = adst[d];
    float4 tm4 = make_float4(0.f, 0.f, 0.f, 0.f);
    float4 um4 = make_float4(0.f, 0.f, 0.f, 0.f);
    float den = 0.f;

    for (int c0 = 0; c0 < deg; c0 += 64) {
        int cc = min(deg - c0, 64);              // wave-uniform
        // preload metadata for up to 64 edges into lane registers
        int exi = 0, eyi = 0; float axl = 0.f;
        if (l < cc) {
            int2 es = edata[base + c0 + l];
            exi = es.x; eyi = es.y;
            axl = asrc[es.y];
        }
        for (int c = 0; c < cc; c += 8) {        // 8 edges per iteration (2x4)
            int i0 = c + g, i1 = c + 4 + g;
            bool v0 = i0 < cc, v1 = i1 < cc;
            int j0 = v0 ? i0 : 0, j1 = v1 ? i1 : 0;
            int ex0 = __shfl(exi, j0), ey0 = __shfl(eyi, j0);
            int ex1 = __shfl(exi, j1), ey1 = __shfl(eyi, j1);
            float ax0 = __shfl(axl, j0), ax1 = __shfl(axl, j1);

            float4 EF0 = *(const float4*)&edge_feat[(size_t)ex0 * 64 + q * 4];
            float4 ZL0 = *(const float4*)&z[(size_t)ey0 * 64 + q * 4];
            float4 EF1 = *(const float4*)&edge_feat[(size_t)ex1 * 64 + q * 4];
            float4 ZL1 = *(const float4*)&z[(size_t)ey1 * 64 + q * 4];

            float p0 = EF0.x * wca4.x + EF0.y * wca4.y + EF0.z * wca4.z + EF0.w * wca4.w;
            p0 += __shfl_xor(p0, 8); p0 += __shfl_xor(p0, 4);
            p0 += __shfl_xor(p0, 2); p0 += __shfl_xor(p0, 1);
            float a0 = ax0 + p0 + ad;
            float s0 = a0 > 0.f ? a0 : 0.01f * a0;
            float e0 = v0 ? __expf(s0) : 0.f;
            tm4.x += e0 * EF0.x; tm4.y += e0 * EF0.y;
            tm4.z += e0 * EF0.z; tm4.w += e0 * EF0.w;
            um4.x += e0 * ZL0.x; um4.y += e0 * ZL0.y;
            um4.z += e0 * ZL0.z; um4.w += e0 * ZL0.w;
            den += e0;

            float p1 = EF1.x * wca4.x + EF1.y * wca4.y + EF1.z * wca4.z + EF1.w * wca4.w;
            p1 += __shfl_xor(p1, 8); p1 += __shfl_xor(p1, 4);
            p1 += __shfl_xor(p1, 2); p1 += __shfl_xor(p1, 1);
            float a1 = ax1 + p1 + ad;
            float s1 = a1 > 0.f ? a1 : 0.01f * a1;
            float e1 = v1 ? __expf(s1) : 0.f;
            tm4.x += e1 * EF1.x; tm4.y += e1 * EF1.y;
            tm4.z += e1 * EF1.z; tm4.w += e1 * EF1.w;
            um4.x += e1 * ZL1.x; um4.y += e1 * ZL1.y;
            um4.z += e1 * ZL1.z; um4.w += e1 * ZL1.w;
            den += e1;
        }
    }

    // combine the 4 edge-slot groups (each holds a full-row partial)
    tm4.x += __shfl_xor(tm4.x, 16); tm4.y += __shfl_xor(tm4.y, 16);
    tm4.z += __shfl_xor(tm4.z, 16); tm4.w += __shfl_xor(tm4.w, 16);
    tm4.x += __shfl_xor(tm4.x, 32); tm4.y += __shfl_xor(tm4.y, 32);
    tm4.z += __shfl_xor(tm4.z, 32); tm4.w += __shfl_xor(tm4.w, 32);
    um4.x += __shfl_xor(um4.x, 16); um4.y += __shfl_xor(um4.y, 16);
    um4.z += __shfl_xor(um4.z, 16); um4.w += __shfl_xor(um4.w, 16);
    um4.x += __shfl_xor(um4.x, 32); um4.y += __shfl_xor(um4.y, 32);
    um4.z += __shfl_xor(um4.z, 32); um4.w += __shfl_xor(um4.w, 32);
    den += __shfl_xor(den, 16); den += __shfl_xor(den, 32);

    if (l < 16) {
        *(float4*)&stu[w][q * 4] = tm4;
        *(float4*)&stu[w][64 + q * 4] = um4;
    }
    __syncthreads();

    if (deg > 0) {
        float acc = 0.f;
        #pragma unroll
        for (int qq = 0; qq < 32; ++qq) {
            float4 wv = *(const float4*)&Wcat[l * 128 + qq * 4];
            float4 tv = *(const float4*)&stu[w][qq * 4];
            acc += wv.x * tv.x + wv.y * tv.y + wv.z * tv.z + wv.w * tv.w;
        }
        out[(size_t)d * 64 + l] = acc / den;
    } else {
        out[(size_t)d * 64 + l] = z[(size_t)d * 64 + l];
    }
}

extern "C" void kernel_launch(void* const* d_in, const int* in_sizes, int n_in,
                              void* d_out, int out_size, void* d_ws, size_t ws_size,
                              hipStream_t stream) {
    const float* h         = (const float*)d_in[0];
    const float* edge_feat = (const float*)d_in[1];
    const int*   src       = (const int*)d_in[2];
    const int*   dst       = (const int*)d_in[3];
    const float* Wn        = (const float*)d_in[4];
    const float* We        = (const float*)d_in[5];
    const float* Wa        = (const float*)d_in[6];
    const float* W2        = (const float*)d_in[7];
    float* out = (float*)d_out;

    char* p = (char*)d_ws;
    float* z      = (float*)p; p += (size_t)N_NODES * 64 * 4;
    float* asrc   = (float*)p; p += (size_t)N_NODES * 4;
    float* adst   = (float*)p; p += (size_t)N_NODES * 4;
    int*   degi   = (int*)p;   p += (size_t)N_NODES * 4;
    int*   start  = (int*)p;   p += (size_t)N_NODES * 4;
    int*   cursor = (int*)p;   p += (size_t)N_NODES * 4;
    int*   partial= (int*)p;   p += (size_t)256 * 4;
    int2*  edata  = (int2*)p;  p += (size_t)N_EDGES * 8;
    float* Wcat   = (float*)p; p += (size_t)64 * 128 * 4;
    float* wca    = (float*)p; p += (size_t)64 * 4;

    hipMemsetAsync(degi, 0, (size_t)N_NODES * 4, stream);

    kw_kernel<<<16, 256, 0, stream>>>(W2, We, Wa, Wcat, wca);
    node_kernel<<<1024, 256, 0, stream>>>(h, Wn, Wa, z, asrc, adst);
    hist_kernel<<<(N_EDGES + 255) / 256, 256, 0, stream>>>(dst, degi);
    scan1_kernel<<<NB1, 256, 0, stream>>>(degi, partial);
    scan2_kernel<<<1, 256, 0, stream>>>(partial);
    scan3_kernel<<<NB1, 256, 0, stream>>>(degi, partial, start, cursor);
    scatter_kernel<<<(N_EDGES + 255) / 256, 256, 0, stream>>>(src, dst, cursor, edata);
    agg_kernel<<<N_NODES / 4, 256, 0, stream>>>(edge_feat, edata, start, degi,
                                                asrc, adst, z, wca, Wcat, out);
}

// Round 6
// 268.442 us; speedup vs baseline: 1.3605x; 1.3026x over previous
//
#include <hip/hip_runtime.h>
#include <math.h>

#define N_NODES 50000
#define N_EDGES 800000
#define NB1 196  // ceil(50000/256)

// ---- bf16 helpers (manual RNE) ----
__device__ __forceinline__ unsigned short f2bf(float f) {
    unsigned u = __float_as_uint(f);
    unsigned r = (u + 0x7FFFu + ((u >> 16) & 1u)) >> 16;
    return (unsigned short)r;
}
__device__ __forceinline__ float bf2f(unsigned short u) {
    return __uint_as_float(((unsigned)u) << 16);
}

// wca[m] = sum_k Wa[64+k]*We[k][m]
__global__ void kw_kernel(const float* __restrict__ We, const float* __restrict__ Wa,
                          float* __restrict__ wca) {
    int t = threadIdx.x;
    if (t < 64) {
        float acc = 0.f;
        #pragma unroll
        for (int k = 0; k < 32; ++k) acc += Wa[64 + k] * We[k * 64 + t];
        wca[t] = acc;
    }
}

// Per-node: z = h@Wn^T (fp32), y16 = bf16(z@W2a^T), asrc = z.Wa[0:64], adst = z.Wa[96:160]
__global__ __launch_bounds__(256) void node_kernel(
    const float* __restrict__ h, const float* __restrict__ Wn,
    const float* __restrict__ W2, const float* __restrict__ Wa,
    float* __restrict__ z, unsigned short* __restrict__ y16,
    float* __restrict__ asrc, float* __restrict__ adst)
{
    __shared__ float sWn[64 * 132];
    __shared__ float sW2a[64 * 68];
    __shared__ float sh[4][128];
    __shared__ float sz[4][64];
    int t = threadIdx.x;
    for (int idx = t; idx < 64 * 128; idx += 256)
        sWn[(idx >> 7) * 132 + (idx & 127)] = Wn[idx];
    for (int idx = t; idx < 64 * 64; idx += 256)
        sW2a[(idx >> 6) * 68 + (idx & 63)] = W2[(idx >> 6) * 96 + (idx & 63)];
    int w = t >> 6, l = t & 63;
    float wa0 = Wa[l], wa2 = Wa[96 + l];
    __syncthreads();
    for (int n0 = blockIdx.x * 4; n0 < N_NODES; n0 += gridDim.x * 4) {
        if (t < 128) {
            int nn = t >> 5, c4 = t & 31;
            int n = n0 + nn;
            if (n < N_NODES)
                ((float4*)&sh[nn][0])[c4] = ((const float4*)h)[(size_t)n * 32 + c4];
        }
        __syncthreads();
        int n = n0 + w;
        if (n < N_NODES) {
            float acc = 0.f;
            #pragma unroll
            for (int qq = 0; qq < 32; ++qq) {
                float4 wv = *(const float4*)&sWn[l * 132 + qq * 4];
                float4 hv = *(const float4*)&sh[w][qq * 4];
                acc += wv.x * hv.x + wv.y * hv.y + wv.z * hv.z + wv.w * hv.w;
            }
            z[(size_t)n * 64 + l] = acc;
            sz[w][l] = acc;
            float p0 = acc * wa0, p1 = acc * wa2;
            #pragma unroll
            for (int off = 32; off; off >>= 1) {
                p0 += __shfl_xor(p0, off);
                p1 += __shfl_xor(p1, off);
            }
            if (l == 0) { asrc[n] = p0; adst[n] = p1; }
        }
        __syncthreads();
        if (n < N_NODES) {
            float acc = 0.f;
            #pragma unroll
            for (int qq = 0; qq < 16; ++qq) {
                float4 wv = *(const float4*)&sW2a[l * 68 + qq * 4];
                float4 zv = *(const float4*)&sz[w][qq * 4];
                acc += wv.x * zv.x + wv.y * zv.y + wv.z * zv.z + wv.w * zv.w;
            }
            y16[(size_t)n * 64 + l] = f2bf(acc);
        }
        __syncthreads();
    }
}

// ---- CSR build ----
__global__ void hist_kernel(const int* __restrict__ dst, int* __restrict__ degi) {
    int e = blockIdx.x * 256 + threadIdx.x;
    if (e < N_EDGES) atomicAdd(&degi[dst[e]], 1);
}

__global__ __launch_bounds__(256) void scan1_kernel(const int* __restrict__ degi,
                                                    int* __restrict__ partial) {
    int t = threadIdx.x, i = blockIdx.x * 256 + t;
    int d = (i < N_NODES) ? degi[i] : 0;
    #pragma unroll
    for (int off = 32; off; off >>= 1) d += __shfl_down(d, off);
    __shared__ int wsum[4];
    if ((t & 63) == 0) wsum[t >> 6] = d;
    __syncthreads();
    if (t == 0) partial[blockIdx.x] = wsum[0] + wsum[1] + wsum[2] + wsum[3];
}

__global__ __launch_bounds__(256) void scan2_kernel(int* __restrict__ partial) {
    __shared__ int s[256];
    int t = threadIdx.x;
    int v = (t < NB1) ? partial[t] : 0;
    s[t] = v; __syncthreads();
    for (int off = 1; off < 256; off <<= 1) {
        int x = (t >= off) ? s[t - off] : 0;
        __syncthreads();
        s[t] += x;
        __syncthreads();
    }
    if (t < NB1) partial[t] = s[t] - v;   // exclusive, in place
}

__global__ __launch_bounds__(256) void scan3_kernel(const int* __restrict__ degi,
                                                    const int* __restrict__ partial,
                                                    int* __restrict__ start,
                                                    int* __restrict__ cursor) {
    __shared__ int s[256];
    int t = threadIdx.x, i = blockIdx.x * 256 + t;
    int d = (i < N_NODES) ? degi[i] : 0;
    s[t] = d; __syncthreads();
    for (int off = 1; off < 256; off <<= 1) {
        int x = (t >= off) ? s[t - off] : 0;
        __syncthreads();
        s[t] += x;
        __syncthreads();
    }
    if (i < N_NODES) {
        int st = partial[blockIdx.x] + s[t] - d;
        start[i] = st;
        cursor[i] = st;
    }
}

// ---- Pass A: stream edge_feat (natural order), compute ex, scatter bf16 row to CSR slot ----
__global__ __launch_bounds__(256) void permute_kernel(
    const float* __restrict__ edge_feat, const int* __restrict__ src,
    const int* __restrict__ dst, const float* __restrict__ asrc,
    const float* __restrict__ adst, const float* __restrict__ wca,
    int* __restrict__ cursor, ushort4* __restrict__ efc, int2* __restrict__ exsrc)
{
    int t = threadIdx.x;
    int e = blockIdx.x * 16 + (t >> 4);      // grid exact: 50000*16 = 800000
    int l = t & 63, q = t & 15;
    float4 wca4 = ((const float4*)wca)[q];
    int s = src[e], d = dst[e];
    float4 v = ((const float4*)edge_feat)[(size_t)e * 16 + q];
    float p = v.x * wca4.x + v.y * wca4.y + v.z * wca4.z + v.w * wca4.w;
    p += __shfl_xor(p, 8); p += __shfl_xor(p, 4);
    p += __shfl_xor(p, 2); p += __shfl_xor(p, 1);
    float a = asrc[s] + p + adst[d];
    float sg = a > 0.f ? a : 0.01f * a;
    float ex = __expf(sg);                   // segmax shift mathematically redundant here
    int pos = 0;
    if (q == 0) pos = atomicAdd(&cursor[d], 1);
    pos = __shfl(pos, l & 48);               // broadcast from group leader
    ushort4 o;
    o.x = f2bf(v.x); o.y = f2bf(v.y); o.z = f2bf(v.z); o.w = f2bf(v.w);
    efc[(size_t)pos * 16 + q] = o;
    if (q == 0) exsrc[pos] = make_int2(__float_as_int(ex), s);
}

// ---- Pass B: per-node walk; ef rows STREAMED (CSR order), y16 gathers L2-resident ----
__global__ __launch_bounds__(256) void agg_kernel(
    const ushort4* __restrict__ efc, const int2* __restrict__ exsrc,
    const ushort4* __restrict__ y16v, const int* __restrict__ start,
    const int* __restrict__ degi, const float* __restrict__ z,
    const float* __restrict__ We, const float* __restrict__ W2,
    float* __restrict__ out)
{
    __shared__ float stu[4][164];    // [0:64)=tm, [64:128)=uy, [128:160)=v32
    __shared__ float sWe[32 * 68];
    __shared__ float sW2b[64 * 36];
    int t = threadIdx.x, w = t >> 6, l = t & 63, g = l >> 4, q = l & 15;
    for (int idx = t; idx < 32 * 64; idx += 256)
        sWe[(idx >> 6) * 68 + (idx & 63)] = We[idx];
    for (int idx = t; idx < 64 * 32; idx += 256)
        sW2b[(idx >> 5) * 36 + (idx & 31)] = W2[(idx >> 5) * 96 + 64 + (idx & 31)];
    __syncthreads();

    int d    = blockIdx.x * 4 + w;           // grid exact: 12500*4 = 50000
    int base = __builtin_amdgcn_readfirstlane(start[d]);
    int deg  = __builtin_amdgcn_readfirstlane(degi[d]);
    float4 tm4 = make_float4(0.f, 0.f, 0.f, 0.f);
    float4 uy4 = make_float4(0.f, 0.f, 0.f, 0.f);
    float den = 0.f;

    for (int c = 0; c < deg; c += 8) {
        int i0 = c + g, i1 = c + 4 + g;
        bool v0 = i0 < deg, v1 = i1 < deg;
        int s0 = base + (v0 ? i0 : 0);
        int s1 = base + (v1 ? i1 : 0);
        int2 m0 = exsrc[s0], m1 = exsrc[s1];
        ushort4 ea = efc[(size_t)s0 * 16 + q];
        ushort4 eb = efc[(size_t)s1 * 16 + q];
        ushort4 ya = y16v[(size_t)m0.y * 16 + q];
        ushort4 yb = y16v[(size_t)m1.y * 16 + q];
        float ex0 = v0 ? __int_as_float(m0.x) : 0.f;
        float ex1 = v1 ? __int_as_float(m1.x) : 0.f;

        tm4.x += ex0 * bf2f(ea.x); tm4.y += ex0 * bf2f(ea.y);
        tm4.z += ex0 * bf2f(ea.z); tm4.w += ex0 * bf2f(ea.w);
        uy4.x += ex0 * bf2f(ya.x); uy4.y += ex0 * bf2f(ya.y);
        uy4.z += ex0 * bf2f(ya.z); uy4.w += ex0 * bf2f(ya.w);
        den += ex0;

        tm4.x += ex1 * bf2f(eb.x); tm4.y += ex1 * bf2f(eb.y);
        tm4.z += ex1 * bf2f(eb.z); tm4.w += ex1 * bf2f(eb.w);
        uy4.x += ex1 * bf2f(yb.x); uy4.y += ex1 * bf2f(yb.y);
        uy4.z += ex1 * bf2f(yb.z); uy4.w += ex1 * bf2f(yb.w);
        den += ex1;
    }

    // combine the 4 edge-slot groups
    tm4.x += __shfl_xor(tm4.x, 16); tm4.y += __shfl_xor(tm4.y, 16);
    tm4.z += __shfl_xor(tm4.z, 16); tm4.w += __shfl_xor(tm4.w, 16);
    tm4.x += __shfl_xor(tm4.x, 32); tm4.y += __shfl_xor(tm4.y, 32);
    tm4.z += __shfl_xor(tm4.z, 32); tm4.w += __shfl_xor(tm4.w, 32);
    uy4.x += __shfl_xor(uy4.x, 16); uy4.y += __shfl_xor(uy4.y, 16);
    uy4.z += __shfl_xor(uy4.z, 16); uy4.w += __shfl_xor(uy4.w, 16);
    uy4.x += __shfl_xor(uy4.x, 32); uy4.y += __shfl_xor(uy4.y, 32);
    uy4.z += __shfl_xor(uy4.z, 32); uy4.w += __shfl_xor(uy4.w, 32);
    den += __shfl_xor(den, 16); den += __shfl_xor(den, 32);

    if (l < 16) {
        *(float4*)&stu[w][q * 4] = tm4;
        *(float4*)&stu[w][64 + q * 4] = uy4;
    }
    // same wave writes+reads stu[w] -> in-order, no barrier needed

    if (deg > 0) {
        if (l < 32) {
            float a = 0.f;
            #pragma unroll
            for (int k = 0; k < 16; ++k) {
                float4 wv = *(const float4*)&sWe[l * 68 + k * 4];
                float4 tv = *(const float4*)&stu[w][k * 4];
                a += wv.x * tv.x + wv.y * tv.y + wv.z * tv.z + wv.w * tv.w;
            }
            stu[w][128 + l] = a;
        }
        float r = 0.f;
        #pragma unroll
        for (int k = 0; k < 8; ++k) {
            float4 wv = *(const float4*)&sW2b[l * 36 + k * 4];
            float4 vv = *(const float4*)&stu[w][128 + k * 4];
            r += wv.x * vv.x + wv.y * vv.y + wv.z * vv.z + wv.w * vv.w;
        }
        out[(size_t)d * 64 + l] = (r + stu[w][64 + l]) / den;
    } else {
        out[(size_t)d * 64 + l] = z[(size_t)d * 64 + l];
    }
}

extern "C" void kernel_launch(void* const* d_in, const int* in_sizes, int n_in,
                              void* d_out, int out_size, void* d_ws, size_t ws_size,
                              hipStream_t stream) {
    const float* h         = (const float*)d_in[0];
    const float* edge_feat = (const float*)d_in[1];
    const int*   src       = (const int*)d_in[2];
    const int*   dst       = (const int*)d_in[3];
    const float* Wn        = (const float*)d_in[4];
    const float* We        = (const float*)d_in[5];
    const float* Wa        = (const float*)d_in[6];
    const float* W2        = (const float*)d_in[7];
    float* out = (float*)d_out;

    char* p = (char*)d_ws;
    float*          z      = (float*)p;          p += (size_t)N_NODES * 64 * 4;   // 12.8 MB
    unsigned short* y16    = (unsigned short*)p; p += (size_t)N_NODES * 64 * 2;   // 6.4 MB
    float*          asrc   = (float*)p;          p += (size_t)N_NODES * 4;
    float*          adst   = (float*)p;          p += (size_t)N_NODES * 4;
    int*            degi   = (int*)p;            p += (size_t)N_NODES * 4;
    int*            start  = (int*)p;            p += (size_t)N_NODES * 4;
    int*            cursor = (int*)p;            p += (size_t)N_NODES * 4;
    int*            partial= (int*)p;            p += (size_t)256 * 4;
    int2*           exsrc  = (int2*)p;           p += (size_t)N_EDGES * 8;        // 6.4 MB
    ushort4*        efc    = (ushort4*)p;        p += (size_t)N_EDGES * 64 * 2;   // 102.4 MB
    float*          wca    = (float*)p;          p += (size_t)64 * 4;

    hipMemsetAsync(degi, 0, (size_t)N_NODES * 4, stream);

    kw_kernel<<<1, 64, 0, stream>>>(We, Wa, wca);
    node_kernel<<<1024, 256, 0, stream>>>(h, Wn, W2, Wa, z, y16, asrc, adst);
    hist_kernel<<<(N_EDGES + 255) / 256, 256, 0, stream>>>(dst, degi);
    scan1_kernel<<<NB1, 256, 0, stream>>>(degi, partial);
    scan2_kernel<<<1, 256, 0, stream>>>(partial);
    scan3_kernel<<<NB1, 256, 0, stream>>>(degi, partial, start, cursor);
    permute_kernel<<<N_EDGES / 16, 256, 0, stream>>>(edge_feat, src, dst, asrc, adst,
                                                     wca, cursor, efc, exsrc);
    agg_kernel<<<N_NODES / 4, 256, 0, stream>>>(efc, exsrc, (const ushort4*)y16,
                                                start, degi, z, We, W2, out);
}

// Round 7
// 260.894 us; speedup vs baseline: 1.3998x; 1.0289x over previous
//
#include <hip/hip_runtime.h>
#include <math.h>

#define N_NODES 50000
#define N_EDGES 800000
#define NB1 196  // ceil(50000/256)

// ---- bf16 helpers (manual RNE) ----
__device__ __forceinline__ unsigned short f2bf(float f) {
    unsigned u = __float_as_uint(f);
    unsigned r = (u + 0x7FFFu + ((u >> 16) & 1u)) >> 16;
    return (unsigned short)r;
}
__device__ __forceinline__ float bf2f(unsigned short u) {
    return __uint_as_float(((unsigned)u) << 16);
}

// wca[m] = sum_k Wa[64+k]*We[k][m]; also zero degi (replaces memset dispatch)
__global__ __launch_bounds__(256) void kw_kernel(const float* __restrict__ We,
                                                 const float* __restrict__ Wa,
                                                 float* __restrict__ wca,
                                                 int* __restrict__ degi) {
    int t = blockIdx.x * 256 + threadIdx.x;
    if (t < N_NODES) degi[t] = 0;
    if (blockIdx.x == 0 && threadIdx.x < 64) {
        float acc = 0.f;
        #pragma unroll
        for (int k = 0; k < 32; ++k) acc += Wa[64 + k] * We[k * 64 + threadIdx.x];
        wca[threadIdx.x] = acc;
    }
}

// Per-node: z = h@Wn^T (fp32), y16 = bf16(z@W2a^T), asrc = z.Wa[0:64], adst = z.Wa[96:160]
__global__ __launch_bounds__(256) void node_kernel(
    const float* __restrict__ h, const float* __restrict__ Wn,
    const float* __restrict__ W2, const float* __restrict__ Wa,
    float* __restrict__ z, unsigned short* __restrict__ y16,
    float* __restrict__ asrc, float* __restrict__ adst)
{
    __shared__ float sWn[64 * 132];
    __shared__ float sW2a[64 * 68];
    __shared__ float sh[4][128];
    __shared__ float sz[4][64];
    int t = threadIdx.x;
    for (int idx = t; idx < 64 * 128; idx += 256)
        sWn[(idx >> 7) * 132 + (idx & 127)] = Wn[idx];
    for (int idx = t; idx < 64 * 64; idx += 256)
        sW2a[(idx >> 6) * 68 + (idx & 63)] = W2[(idx >> 6) * 96 + (idx & 63)];
    int w = t >> 6, l = t & 63;
    float wa0 = Wa[l], wa2 = Wa[96 + l];
    __syncthreads();
    for (int n0 = blockIdx.x * 4; n0 < N_NODES; n0 += gridDim.x * 4) {
        if (t < 128) {
            int nn = t >> 5, c4 = t & 31;
            int n = n0 + nn;
            if (n < N_NODES)
                ((float4*)&sh[nn][0])[c4] = ((const float4*)h)[(size_t)n * 32 + c4];
        }
        __syncthreads();
        int n = n0 + w;
        if (n < N_NODES) {
            float acc = 0.f;
            #pragma unroll
            for (int qq = 0; qq < 32; ++qq) {
                float4 wv = *(const float4*)&sWn[l * 132 + qq * 4];
                float4 hv = *(const float4*)&sh[w][qq * 4];
                acc += wv.x * hv.x + wv.y * hv.y + wv.z * hv.z + wv.w * hv.w;
            }
            z[(size_t)n * 64 + l] = acc;
            sz[w][l] = acc;
            float p0 = acc * wa0, p1 = acc * wa2;
            #pragma unroll
            for (int off = 32; off; off >>= 1) {
                p0 += __shfl_xor(p0, off);
                p1 += __shfl_xor(p1, off);
            }
            if (l == 0) { asrc[n] = p0; adst[n] = p1; }
        }
        __syncthreads();
        if (n < N_NODES) {
            float acc = 0.f;
            #pragma unroll
            for (int qq = 0; qq < 16; ++qq) {
                float4 wv = *(const float4*)&sW2a[l * 68 + qq * 4];
                float4 zv = *(const float4*)&sz[w][qq * 4];
                acc += wv.x * zv.x + wv.y * zv.y + wv.z * zv.z + wv.w * zv.w;
            }
            y16[(size_t)n * 64 + l] = f2bf(acc);
        }
        __syncthreads();
    }
}

// ---- CSR build: hist also assigns each edge its within-node rank (coalesced write) ----
__global__ void hist_kernel(const int* __restrict__ dst, int* __restrict__ degi,
                            int* __restrict__ ranks) {
    int e = blockIdx.x * 256 + threadIdx.x;
    if (e < N_EDGES) ranks[e] = atomicAdd(&degi[dst[e]], 1);
}

__global__ __launch_bounds__(256) void scan1_kernel(const int* __restrict__ degi,
                                                    int* __restrict__ partial) {
    int t = threadIdx.x, i = blockIdx.x * 256 + t;
    int d = (i < N_NODES) ? degi[i] : 0;
    #pragma unroll
    for (int off = 32; off; off >>= 1) d += __shfl_down(d, off);
    __shared__ int wsum[4];
    if ((t & 63) == 0) wsum[t >> 6] = d;
    __syncthreads();
    if (t == 0) partial[blockIdx.x] = wsum[0] + wsum[1] + wsum[2] + wsum[3];
}

__global__ __launch_bounds__(256) void scan2_kernel(int* __restrict__ partial) {
    __shared__ int s[256];
    int t = threadIdx.x;
    int v = (t < NB1) ? partial[t] : 0;
    s[t] = v; __syncthreads();
    for (int off = 1; off < 256; off <<= 1) {
        int x = (t >= off) ? s[t - off] : 0;
        __syncthreads();
        s[t] += x;
        __syncthreads();
    }
    if (t < NB1) partial[t] = s[t] - v;   // exclusive, in place
}

__global__ __launch_bounds__(256) void scan3_kernel(const int* __restrict__ degi,
                                                    const int* __restrict__ partial,
                                                    int* __restrict__ start) {
    __shared__ int s[256];
    int t = threadIdx.x, i = blockIdx.x * 256 + t;
    int d = (i < N_NODES) ? degi[i] : 0;
    s[t] = d; __syncthreads();
    for (int off = 1; off < 256; off <<= 1) {
        int x = (t >= off) ? s[t - off] : 0;
        __syncthreads();
        s[t] += x;
        __syncthreads();
    }
    if (i < N_NODES) start[i] = partial[blockIdx.x] + s[t] - d;
}

// ---- Pass A: stream edge_feat, compute ex, write bf16 row + (ex,src) meta as ONE
//      contiguous 136B burst per slot (stride 17 ushort4). No atomics here. ----
__global__ __launch_bounds__(256) void permute_kernel(
    const float* __restrict__ edge_feat, const int* __restrict__ src,
    const int* __restrict__ dst, const int* __restrict__ ranks,
    const float* __restrict__ asrc, const float* __restrict__ adst,
    const int* __restrict__ start, const float* __restrict__ wca,
    ushort4* __restrict__ efc)
{
    int t = threadIdx.x;
    int e = blockIdx.x * 16 + (t >> 4);      // grid exact: 50000*16 = 800000
    int q = t & 15;
    float4 wca4 = ((const float4*)wca)[q];
    int s = src[e], d = dst[e];
    float4 v = ((const float4*)edge_feat)[(size_t)e * 16 + q];
    float p = v.x * wca4.x + v.y * wca4.y + v.z * wca4.z + v.w * wca4.w;
    p += __shfl_xor(p, 8); p += __shfl_xor(p, 4);
    p += __shfl_xor(p, 2); p += __shfl_xor(p, 1);
    float a = asrc[s] + p + adst[d];
    float sg = a > 0.f ? a : 0.01f * a;
    float ex = __expf(sg);                   // segmax shift mathematically redundant here
    int slot = start[d] + ranks[e];
    size_t rb = (size_t)slot * 17;
    ushort4 o;
    o.x = f2bf(v.x); o.y = f2bf(v.y); o.z = f2bf(v.z); o.w = f2bf(v.w);
    efc[rb + q] = o;
    if (q == 0) {
        int2 m = make_int2(__float_as_int(ex), s);
        *(int2*)&efc[rb + 16] = m;
    }
}

// ---- Pass B: per-node walk; ef rows + meta STREAMED (CSR order), y16 gathers L3-hot ----
__global__ __launch_bounds__(256) void agg_kernel(
    const ushort4* __restrict__ efc, const ushort4* __restrict__ y16v,
    const int* __restrict__ start, const int* __restrict__ degi,
    const float* __restrict__ z, const float* __restrict__ We,
    const float* __restrict__ W2, float* __restrict__ out)
{
    __shared__ float stu[4][164];    // [0:64)=tm, [64:128)=uy, [128:160)=v32
    __shared__ float sWe[32 * 68];
    __shared__ float sW2b[64 * 36];
    int t = threadIdx.x, w = t >> 6, l = t & 63, g = l >> 4, q = l & 15;
    for (int idx = t; idx < 32 * 64; idx += 256)
        sWe[(idx >> 6) * 68 + (idx & 63)] = We[idx];
    for (int idx = t; idx < 64 * 32; idx += 256)
        sW2b[(idx >> 5) * 36 + (idx & 31)] = W2[(idx >> 5) * 96 + 64 + (idx & 31)];
    __syncthreads();

    int d    = blockIdx.x * 4 + w;           // grid exact: 12500*4 = 50000
    int base = __builtin_amdgcn_readfirstlane(start[d]);
    int deg  = __builtin_amdgcn_readfirstlane(degi[d]);
    float4 tm4 = make_float4(0.f, 0.f, 0.f, 0.f);
    float4 uy4 = make_float4(0.f, 0.f, 0.f, 0.f);
    float den = 0.f;

    for (int c = 0; c < deg; c += 8) {
        int i0 = c + g, i1 = c + 4 + g;
        bool v0 = i0 < deg, v1 = i1 < deg;
        size_t r0 = (size_t)(base + (v0 ? i0 : 0)) * 17;
        size_t r1 = (size_t)(base + (v1 ? i1 : 0)) * 17;
        ushort4 ea = efc[r0 + q];
        ushort4 eb = efc[r1 + q];
        int2 m0 = *(const int2*)&efc[r0 + 16];
        int2 m1 = *(const int2*)&efc[r1 + 16];
        ushort4 ya = y16v[(size_t)m0.y * 16 + q];
        ushort4 yb = y16v[(size_t)m1.y * 16 + q];
        float ex0 = v0 ? __int_as_float(m0.x) : 0.f;
        float ex1 = v1 ? __int_as_float(m1.x) : 0.f;

        tm4.x += ex0 * bf2f(ea.x); tm4.y += ex0 * bf2f(ea.y);
        tm4.z += ex0 * bf2f(ea.z); tm4.w += ex0 * bf2f(ea.w);
        uy4.x += ex0 * bf2f(ya.x); uy4.y += ex0 * bf2f(ya.y);
        uy4.z += ex0 * bf2f(ya.z); uy4.w += ex0 * bf2f(ya.w);
        den += ex0;

        tm4.x += ex1 * bf2f(eb.x); tm4.y += ex1 * bf2f(eb.y);
        tm4.z += ex1 * bf2f(eb.z); tm4.w += ex1 * bf2f(eb.w);
        uy4.x += ex1 * bf2f(yb.x); uy4.y += ex1 * bf2f(yb.y);
        uy4.z += ex1 * bf2f(yb.z); uy4.w += ex1 * bf2f(yb.w);
        den += ex1;
    }

    // combine the 4 edge-slot groups
    tm4.x += __shfl_xor(tm4.x, 16); tm4.y += __shfl_xor(tm4.y, 16);
    tm4.z += __shfl_xor(tm4.z, 16); tm4.w += __shfl_xor(tm4.w, 16);
    tm4.x += __shfl_xor(tm4.x, 32); tm4.y += __shfl_xor(tm4.y, 32);
    tm4.z += __shfl_xor(tm4.z, 32); tm4.w += __shfl_xor(tm4.w, 32);
    uy4.x += __shfl_xor(uy4.x, 16); uy4.y += __shfl_xor(uy4.y, 16);
    uy4.z += __shfl_xor(uy4.z, 16); uy4.w += __shfl_xor(uy4.w, 16);
    uy4.x += __shfl_xor(uy4.x, 32); uy4.y += __shfl_xor(uy4.y, 32);
    uy4.z += __shfl_xor(uy4.z, 32); uy4.w += __shfl_xor(uy4.w, 32);
    den += __shfl_xor(den, 16); den += __shfl_xor(den, 32);

    if (l < 16) {
        *(float4*)&stu[w][q * 4] = tm4;
        *(float4*)&stu[w][64 + q * 4] = uy4;
    }
    // same wave writes+reads stu[w] -> in-order, no barrier needed

    if (deg > 0) {
        if (l < 32) {
            float a = 0.f;
            #pragma unroll
            for (int k = 0; k < 16; ++k) {
                float4 wv = *(const float4*)&sWe[l * 68 + k * 4];
                float4 tv = *(const float4*)&stu[w][k * 4];
                a += wv.x * tv.x + wv.y * tv.y + wv.z * tv.z + wv.w * tv.w;
            }
            stu[w][128 + l] = a;
        }
        float r = 0.f;
        #pragma unroll
        for (int k = 0; k < 8; ++k) {
            float4 wv = *(const float4*)&sW2b[l * 36 + k * 4];
            float4 vv = *(const float4*)&stu[w][128 + k * 4];
            r += wv.x * vv.x + wv.y * vv.y + wv.z * vv.z + wv.w * vv.w;
        }
        out[(size_t)d * 64 + l] = (r + stu[w][64 + l]) / den;
    } else {
        out[(size_t)d * 64 + l] = z[(size_t)d * 64 + l];
    }
}

extern "C" void kernel_launch(void* const* d_in, const int* in_sizes, int n_in,
                              void* d_out, int out_size, void* d_ws, size_t ws_size,
                              hipStream_t stream) {
    const float* h         = (const float*)d_in[0];
    const float* edge_feat = (const float*)d_in[1];
    const int*   src       = (const int*)d_in[2];
    const int*   dst       = (const int*)d_in[3];
    const float* Wn        = (const float*)d_in[4];
    const float* We        = (const float*)d_in[5];
    const float* Wa        = (const float*)d_in[6];
    const float* W2        = (const float*)d_in[7];
    float* out = (float*)d_out;

    char* p = (char*)d_ws;
    float*          z      = (float*)p;          p += (size_t)N_NODES * 64 * 4;   // 12.8 MB
    unsigned short* y16    = (unsigned short*)p; p += (size_t)N_NODES * 64 * 2;   // 6.4 MB
    float*          asrc   = (float*)p;          p += (size_t)N_NODES * 4;
    float*          adst   = (float*)p;          p += (size_t)N_NODES * 4;
    int*            degi   = (int*)p;            p += (size_t)N_NODES * 4;
    int*            start  = (int*)p;            p += (size_t)N_NODES * 4;
    int*            ranks  = (int*)p;            p += (size_t)N_EDGES * 4;        // 3.2 MB
    int*            partial= (int*)p;            p += (size_t)256 * 4;
    ushort4*        efc    = (ushort4*)p;        p += (size_t)N_EDGES * 17 * 8;   // 108.8 MB
    float*          wca    = (float*)p;          p += (size_t)64 * 4;

    kw_kernel<<<NB1, 256, 0, stream>>>(We, Wa, wca, degi);
    node_kernel<<<1024, 256, 0, stream>>>(h, Wn, W2, Wa, z, y16, asrc, adst);
    hist_kernel<<<(N_EDGES + 255) / 256, 256, 0, stream>>>(dst, degi, ranks);
    scan1_kernel<<<NB1, 256, 0, stream>>>(degi, partial);
    scan2_kernel<<<1, 256, 0, stream>>>(partial);
    scan3_kernel<<<NB1, 256, 0, stream>>>(degi, partial, start);
    permute_kernel<<<N_EDGES / 16, 256, 0, stream>>>(edge_feat, src, dst, ranks,
                                                     asrc, adst, start, wca, efc);
    agg_kernel<<<N_NODES / 4, 256, 0, stream>>>(efc, (const ushort4*)y16,
                                                start, degi, z, We, W2, out);
}

// Round 8
// 232.160 us; speedup vs baseline: 1.5731x; 1.1238x over previous
//
#include <hip/hip_runtime.h>
#include <math.h>

#define N_NODES 50000
#define N_EDGES 800000
#define NB1 196  // ceil(50000/256)

typedef __attribute__((ext_vector_type(8))) short bf16x8;
typedef __attribute__((ext_vector_type(4))) float f32x4;

// ---- bf16 helpers (manual RNE) ----
__device__ __forceinline__ unsigned short f2bf(float f) {
    unsigned u = __float_as_uint(f);
    unsigned r = (u + 0x7FFFu + ((u >> 16) & 1u)) >> 16;
    return (unsigned short)r;
}
__device__ __forceinline__ float bf2f(unsigned short u) {
    return __uint_as_float(((unsigned)u) << 16);
}
__device__ __forceinline__ unsigned pack2bf(float a, float b) {
    return (unsigned)f2bf(a) | ((unsigned)f2bf(b) << 16);
}

// Build MFMA B-fragments of We^T (bf16) + zero degi.
// Bpack element index = ((s*2+n)*64 + lane)*8 + j  ==  B[k=32s+8*(lane>>4)+j][col=16n+(lane&15)]
// where B[k][j] = We[j][k].
__global__ __launch_bounds__(256) void kw_kernel(const float* __restrict__ We,
                                                 short* __restrict__ Bpack,
                                                 int* __restrict__ degi) {
    int t = blockIdx.x * 256 + threadIdx.x;
    if (t < N_NODES) degi[t] = 0;
    if (t < 2048) {
        int s = t >> 10, n = (t >> 9) & 1, lane = (t >> 3) & 63, j = t & 7;
        float v = We[(16 * n + (lane & 15)) * 64 + 32 * s + 8 * (lane >> 4) + j];
        Bpack[t] = (short)f2bf(v);
    }
}

// Per-node: z = h@Wn^T (fp32), y16 = bf16(z@W2a^T), asrc = z.Wa[0:64], adst = z.Wa[96:160]
__global__ __launch_bounds__(256) void node_kernel(
    const float* __restrict__ h, const float* __restrict__ Wn,
    const float* __restrict__ W2, const float* __restrict__ Wa,
    float* __restrict__ z, unsigned short* __restrict__ y16,
    float* __restrict__ asrc, float* __restrict__ adst)
{
    __shared__ float sWn[64 * 132];
    __shared__ float sW2a[64 * 68];
    __shared__ float sh[4][128];
    __shared__ float sz[4][64];
    int t = threadIdx.x;
    for (int idx = t; idx < 64 * 128; idx += 256)
        sWn[(idx >> 7) * 132 + (idx & 127)] = Wn[idx];
    for (int idx = t; idx < 64 * 64; idx += 256)
        sW2a[(idx >> 6) * 68 + (idx & 63)] = W2[(idx >> 6) * 96 + (idx & 63)];
    int w = t >> 6, l = t & 63;
    float wa0 = Wa[l], wa2 = Wa[96 + l];
    __syncthreads();
    for (int n0 = blockIdx.x * 4; n0 < N_NODES; n0 += gridDim.x * 4) {
        if (t < 128) {
            int nn = t >> 5, c4 = t & 31;
            int n = n0 + nn;
            if (n < N_NODES)
                ((float4*)&sh[nn][0])[c4] = ((const float4*)h)[(size_t)n * 32 + c4];
        }
        __syncthreads();
        int n = n0 + w;
        if (n < N_NODES) {
            float acc = 0.f;
            #pragma unroll
            for (int qq = 0; qq < 32; ++qq) {
                float4 wv = *(const float4*)&sWn[l * 132 + qq * 4];
                float4 hv = *(const float4*)&sh[w][qq * 4];
                acc += wv.x * hv.x + wv.y * hv.y + wv.z * hv.z + wv.w * hv.w;
            }
            z[(size_t)n * 64 + l] = acc;
            sz[w][l] = acc;
            float p0 = acc * wa0, p1 = acc * wa2;
            #pragma unroll
            for (int off = 32; off; off >>= 1) {
                p0 += __shfl_xor(p0, off);
                p1 += __shfl_xor(p1, off);
            }
            if (l == 0) { asrc[n] = p0; adst[n] = p1; }
        }
        __syncthreads();
        if (n < N_NODES) {
            float acc = 0.f;
            #pragma unroll
            for (int qq = 0; qq < 16; ++qq) {
                float4 wv = *(const float4*)&sW2a[l * 68 + qq * 4];
                float4 zv = *(const float4*)&sz[w][qq * 4];
                acc += wv.x * zv.x + wv.y * zv.y + wv.z * zv.z + wv.w * zv.w;
            }
            y16[(size_t)n * 64 + l] = f2bf(acc);
        }
        __syncthreads();
    }
}

// ---- CSR build ----
__global__ void hist_kernel(const int* __restrict__ dst, int* __restrict__ degi,
                            int* __restrict__ ranks) {
    int e = blockIdx.x * 256 + threadIdx.x;
    if (e < N_EDGES) ranks[e] = atomicAdd(&degi[dst[e]], 1);
}

__global__ __launch_bounds__(256) void scan1_kernel(const int* __restrict__ degi,
                                                    int* __restrict__ partial) {
    int t = threadIdx.x, i = blockIdx.x * 256 + t;
    int d = (i < N_NODES) ? degi[i] : 0;
    #pragma unroll
    for (int off = 32; off; off >>= 1) d += __shfl_down(d, off);
    __shared__ int wsum[4];
    if ((t & 63) == 0) wsum[t >> 6] = d;
    __syncthreads();
    if (t == 0) partial[blockIdx.x] = wsum[0] + wsum[1] + wsum[2] + wsum[3];
}

__global__ __launch_bounds__(256) void scan2_kernel(int* __restrict__ partial) {
    __shared__ int s[256];
    int t = threadIdx.x;
    int v = (t < NB1) ? partial[t] : 0;
    s[t] = v; __syncthreads();
    for (int off = 1; off < 256; off <<= 1) {
        int x = (t >= off) ? s[t - off] : 0;
        __syncthreads();
        s[t] += x;
        __syncthreads();
    }
    if (t < NB1) partial[t] = s[t] - v;   // exclusive, in place
}

__global__ __launch_bounds__(256) void scan3_kernel(const int* __restrict__ degi,
                                                    const int* __restrict__ partial,
                                                    int* __restrict__ start) {
    __shared__ int s[256];
    int t = threadIdx.x, i = blockIdx.x * 256 + t;
    int d = (i < N_NODES) ? degi[i] : 0;
    s[t] = d; __syncthreads();
    for (int off = 1; off < 256; off <<= 1) {
        int x = (t >= off) ? s[t - off] : 0;
        __syncthreads();
        s[t] += x;
        __syncthreads();
    }
    if (i < N_NODES) start[i] = partial[blockIdx.x] + s[t] - d;
}

// ---- Pass A: stream edge_feat; MFMA computes g = ef@We^T (16 edges/wave);
//      logit from g; store 72B slot: 16 uints of (g_j, g_{j+16}) bf16-pairs + (ex,src) ----
__global__ __launch_bounds__(256) void permute_kernel(
    const float* __restrict__ edge_feat, const int* __restrict__ src,
    const int* __restrict__ dst, const int* __restrict__ ranks,
    const float* __restrict__ asrc, const float* __restrict__ adst,
    const int* __restrict__ start, const float* __restrict__ Wa,
    const short* __restrict__ Bpack, unsigned* __restrict__ gslot)
{
    int t = threadIdx.x, w = t >> 6, l = t & 63;
    int eb = blockIdx.x * 64 + w * 16;     // grid exact: 12500*64 = 800000
    int c = l & 15, G = l >> 4;

    // B fragments (wave-invariant, 16 VGPRs)
    const bf16x8* Bp = (const bf16x8*)Bpack;
    bf16x8 b00 = Bp[0 * 64 + l];   // s=0,n=0
    bf16x8 b01 = Bp[1 * 64 + l];   // s=0,n=1
    bf16x8 b10 = Bp[2 * 64 + l];   // s=1,n=0
    bf16x8 b11 = Bp[3 * 64 + l];   // s=1,n=1

    // per-edge meta in lanes 0..15
    int se = 0, slot = 0; float apre = 0.f;
    if (l < 16) {
        int e = eb + l;
        se = src[e];
        int de = dst[e];
        slot = start[de] + ranks[e];
        apre = asrc[se] + adst[de];
    }

    // A fragments: lane holds ef[edge eb+c][k = 32s + 8G + j]
    const float* efr = edge_feat + (size_t)(eb + c) * 64 + G * 8;
    float4 a0lo = *(const float4*)(efr);
    float4 a0hi = *(const float4*)(efr + 4);
    float4 a1lo = *(const float4*)(efr + 32);
    float4 a1hi = *(const float4*)(efr + 36);
    bf16x8 a0, a1;
    a0[0] = (short)f2bf(a0lo.x); a0[1] = (short)f2bf(a0lo.y);
    a0[2] = (short)f2bf(a0lo.z); a0[3] = (short)f2bf(a0lo.w);
    a0[4] = (short)f2bf(a0hi.x); a0[5] = (short)f2bf(a0hi.y);
    a0[6] = (short)f2bf(a0hi.z); a0[7] = (short)f2bf(a0hi.w);
    a1[0] = (short)f2bf(a1lo.x); a1[1] = (short)f2bf(a1lo.y);
    a1[2] = (short)f2bf(a1lo.z); a1[3] = (short)f2bf(a1lo.w);
    a1[4] = (short)f2bf(a1hi.x); a1[5] = (short)f2bf(a1hi.y);
    a1[6] = (short)f2bf(a1hi.z); a1[7] = (short)f2bf(a1hi.w);

    f32x4 acc0 = {0.f, 0.f, 0.f, 0.f};
    f32x4 acc1 = {0.f, 0.f, 0.f, 0.f};
    acc0 = __builtin_amdgcn_mfma_f32_16x16x32_bf16(a0, b00, acc0, 0, 0, 0);
    acc0 = __builtin_amdgcn_mfma_f32_16x16x32_bf16(a1, b10, acc0, 0, 0, 0);
    acc1 = __builtin_amdgcn_mfma_f32_16x16x32_bf16(a0, b01, acc1, 0, 0, 0);
    acc1 = __builtin_amdgcn_mfma_f32_16x16x32_bf16(a1, b11, acc1, 0, 0, 0);
    // acc0[r] = g[edge eb+4G+r][j=c], acc1[r] = g[..][j=16+c]

    float wam0 = Wa[64 + c], wam1 = Wa[80 + c];

    #pragma unroll
    for (int r = 0; r < 4; ++r) {
        float p = wam0 * acc0[r] + wam1 * acc1[r];
        p += __shfl_xor(p, 1); p += __shfl_xor(p, 2);
        p += __shfl_xor(p, 4); p += __shfl_xor(p, 8);
        int el = 4 * G + r;
        float a = __shfl(apre, el) + p;
        float sg = a > 0.f ? a : 0.01f * a;
        float ex = __expf(sg);           // segmax shift mathematically redundant
        int sl = __shfl(slot, el);
        int sr = __shfl(se, el);
        gslot[(size_t)sl * 18 + c] = pack2bf(acc0[r], acc1[r]);
        if (c == 0)
            *(int2*)&gslot[(size_t)sl * 18 + 16] = make_int2(__float_as_int(ex), sr);
    }
}

// ---- Pass B: per-node walk; g-slots streamed (CSR order), y16 gathers L2-hot ----
__global__ __launch_bounds__(256) void agg_kernel(
    const unsigned* __restrict__ gslot, const ushort4* __restrict__ y16v,
    const int* __restrict__ start, const int* __restrict__ degi,
    const float* __restrict__ z, const float* __restrict__ W2,
    float* __restrict__ out)
{
    __shared__ float stu[4][164];    // [64:128)=uy, [128:160)=v32 (=We@tm, already projected)
    __shared__ float sW2b[64 * 36];
    int t = threadIdx.x, w = t >> 6, l = t & 63, g = l >> 4, q = l & 15;
    for (int idx = t; idx < 64 * 32; idx += 256)
        sW2b[(idx >> 5) * 36 + (idx & 31)] = W2[(idx >> 5) * 96 + 64 + (idx & 31)];
    __syncthreads();

    int d    = blockIdx.x * 4 + w;           // grid exact: 12500*4 = 50000
    int base = __builtin_amdgcn_readfirstlane(start[d]);
    int deg  = __builtin_amdgcn_readfirstlane(degi[d]);
    float2 tg = make_float2(0.f, 0.f);
    float4 uy4 = make_float4(0.f, 0.f, 0.f, 0.f);
    float den = 0.f;

    for (int c = 0; c < deg; c += 8) {
        int i0 = c + g, i1 = c + 4 + g;
        bool v0 = i0 < deg, v1 = i1 < deg;
        const unsigned* p0 = gslot + (size_t)(base + (v0 ? i0 : 0)) * 18;
        const unsigned* p1 = gslot + (size_t)(base + (v1 ? i1 : 0)) * 18;
        unsigned ga = p0[q], gb = p1[q];
        int2 m0 = *(const int2*)(p0 + 16);
        int2 m1 = *(const int2*)(p1 + 16);
        ushort4 ya = y16v[(size_t)m0.y * 16 + q];
        ushort4 yb = y16v[(size_t)m1.y * 16 + q];
        float ex0 = v0 ? __int_as_float(m0.x) : 0.f;
        float ex1 = v1 ? __int_as_float(m1.x) : 0.f;

        tg.x += ex0 * bf2f((unsigned short)(ga & 0xffffu));
        tg.y += ex0 * bf2f((unsigned short)(ga >> 16));
        uy4.x += ex0 * bf2f(ya.x); uy4.y += ex0 * bf2f(ya.y);
        uy4.z += ex0 * bf2f(ya.z); uy4.w += ex0 * bf2f(ya.w);
        den += ex0;

        tg.x += ex1 * bf2f((unsigned short)(gb & 0xffffu));
        tg.y += ex1 * bf2f((unsigned short)(gb >> 16));
        uy4.x += ex1 * bf2f(yb.x); uy4.y += ex1 * bf2f(yb.y);
        uy4.z += ex1 * bf2f(yb.z); uy4.w += ex1 * bf2f(yb.w);
        den += ex1;
    }

    // combine the 4 edge-slot groups
    tg.x += __shfl_xor(tg.x, 16); tg.x += __shfl_xor(tg.x, 32);
    tg.y += __shfl_xor(tg.y, 16); tg.y += __shfl_xor(tg.y, 32);
    uy4.x += __shfl_xor(uy4.x, 16); uy4.x += __shfl_xor(uy4.x, 32);
    uy4.y += __shfl_xor(uy4.y, 16); uy4.y += __shfl_xor(uy4.y, 32);
    uy4.z += __shfl_xor(uy4.z, 16); uy4.z += __shfl_xor(uy4.z, 32);
    uy4.w += __shfl_xor(uy4.w, 16); uy4.w += __shfl_xor(uy4.w, 32);
    den += __shfl_xor(den, 16); den += __shfl_xor(den, 32);

    if (l < 16) {
        *(float4*)&stu[w][64 + q * 4] = uy4;
        stu[w][128 + q] = tg.x;        // v32[j=q]
        stu[w][144 + q] = tg.y;        // v32[j=16+q]
    }
    // same wave writes+reads stu[w] -> in-order, no barrier needed

    if (deg > 0) {
        float r = 0.f;
        #pragma unroll
        for (int k = 0; k < 8; ++k) {
            float4 wv = *(const float4*)&sW2b[l * 36 + k * 4];
            float4 vv = *(const float4*)&stu[w][128 + k * 4];
            r += wv.x * vv.x + wv.y * vv.y + wv.z * vv.z + wv.w * vv.w;
        }
        out[(size_t)d * 64 + l] = (r + stu[w][64 + l]) / den;
    } else {
        out[(size_t)d * 64 + l] = z[(size_t)d * 64 + l];
    }
}

extern "C" void kernel_launch(void* const* d_in, const int* in_sizes, int n_in,
                              void* d_out, int out_size, void* d_ws, size_t ws_size,
                              hipStream_t stream) {
    const float* h         = (const float*)d_in[0];
    const float* edge_feat = (const float*)d_in[1];
    const int*   src       = (const int*)d_in[2];
    const int*   dst       = (const int*)d_in[3];
    const float* Wn        = (const float*)d_in[4];
    const float* We        = (const float*)d_in[5];
    const float* Wa        = (const float*)d_in[6];
    const float* W2        = (const float*)d_in[7];
    float* out = (float*)d_out;

    char* p = (char*)d_ws;
    float*          z      = (float*)p;          p += (size_t)N_NODES * 64 * 4;   // 12.8 MB
    unsigned short* y16    = (unsigned short*)p; p += (size_t)N_NODES * 64 * 2;   // 6.4 MB
    float*          asrc   = (float*)p;          p += (size_t)N_NODES * 4;
    float*          adst   = (float*)p;          p += (size_t)N_NODES * 4;
    int*            degi   = (int*)p;            p += (size_t)N_NODES * 4;
    int*            start  = (int*)p;            p += (size_t)N_NODES * 4;
    int*            ranks  = (int*)p;            p += (size_t)N_EDGES * 4;        // 3.2 MB
    int*            partial= (int*)p;            p += (size_t)256 * 4;
    short*          Bpack  = (short*)p;          p += (size_t)2048 * 2;           // 4 KB
    unsigned*       gslot  = (unsigned*)p;       p += (size_t)N_EDGES * 18 * 4;   // 57.6 MB

    kw_kernel<<<NB1, 256, 0, stream>>>(We, Bpack, degi);
    node_kernel<<<1024, 256, 0, stream>>>(h, Wn, W2, Wa, z, y16, asrc, adst);
    hist_kernel<<<(N_EDGES + 255) / 256, 256, 0, stream>>>(dst, degi, ranks);
    scan1_kernel<<<NB1, 256, 0, stream>>>(degi, partial);
    scan2_kernel<<<1, 256, 0, stream>>>(partial);
    scan3_kernel<<<NB1, 256, 0, stream>>>(degi, partial, start);
    permute_kernel<<<N_EDGES / 64, 256, 0, stream>>>(edge_feat, src, dst, ranks,
                                                     asrc, adst, start, Wa, Bpack, gslot);
    agg_kernel<<<N_NODES / 4, 256, 0, stream>>>(gslot, (const ushort4*)y16,
                                                start, degi, z, W2, out);
}

// Round 9
// 231.251 us; speedup vs baseline: 1.5792x; 1.0039x over previous
//
#include <hip/hip_runtime.h>
#include <math.h>

#define N_NODES 50000
#define N_EDGES 800000
#define NB1 196  // ceil(50000/256)

typedef __attribute__((ext_vector_type(8))) short bf16x8;
typedef __attribute__((ext_vector_type(4))) float f32x4;

// ---- bf16 helpers (manual RNE) ----
__device__ __forceinline__ unsigned short f2bf(float f) {
    unsigned u = __float_as_uint(f);
    unsigned r = (u + 0x7FFFu + ((u >> 16) & 1u)) >> 16;
    return (unsigned short)r;
}
__device__ __forceinline__ float bf2f(unsigned short u) {
    return __uint_as_float(((unsigned)u) << 16);
}
__device__ __forceinline__ unsigned pack2bf(float a, float b) {
    return (unsigned)f2bf(a) | ((unsigned)f2bf(b) << 16);
}

// Build MFMA B-fragments of We^T (bf16) + zero degi.
// Bpack element index = ((s*2+n)*64 + lane)*8 + j  ==  B[k=32s+8*(lane>>4)+j][col=16n+(lane&15)]
// where B[k][j] = We[j][k].
__global__ __launch_bounds__(256) void kw_kernel(const float* __restrict__ We,
                                                 short* __restrict__ Bpack,
                                                 int* __restrict__ degi) {
    int t = blockIdx.x * 256 + threadIdx.x;
    if (t < N_NODES) degi[t] = 0;
    if (t < 2048) {
        int s = t >> 10, n = (t >> 9) & 1, lane = (t >> 3) & 63, j = t & 7;
        float v = We[(16 * n + (lane & 15)) * 64 + 32 * s + 8 * (lane >> 4) + j];
        Bpack[t] = (short)f2bf(v);
    }
}

// Per-node: z = h@Wn^T (fp32), y16 = bf16(z@W2a^T), asrc = z.Wa[0:64], adst = z.Wa[96:160]
__global__ __launch_bounds__(256) void node_kernel(
    const float* __restrict__ h, const float* __restrict__ Wn,
    const float* __restrict__ W2, const float* __restrict__ Wa,
    float* __restrict__ z, unsigned short* __restrict__ y16,
    float* __restrict__ asrc, float* __restrict__ adst)
{
    __shared__ float sWn[64 * 132];
    __shared__ float sW2a[64 * 68];
    __shared__ float sh[4][128];
    __shared__ float sz[4][64];
    int t = threadIdx.x;
    for (int idx = t; idx < 64 * 128; idx += 256)
        sWn[(idx >> 7) * 132 + (idx & 127)] = Wn[idx];
    for (int idx = t; idx < 64 * 64; idx += 256)
        sW2a[(idx >> 6) * 68 + (idx & 63)] = W2[(idx >> 6) * 96 + (idx & 63)];
    int w = t >> 6, l = t & 63;
    float wa0 = Wa[l], wa2 = Wa[96 + l];
    __syncthreads();
    for (int n0 = blockIdx.x * 4; n0 < N_NODES; n0 += gridDim.x * 4) {
        if (t < 128) {
            int nn = t >> 5, c4 = t & 31;
            int n = n0 + nn;
            if (n < N_NODES)
                ((float4*)&sh[nn][0])[c4] = ((const float4*)h)[(size_t)n * 32 + c4];
        }
        __syncthreads();
        int n = n0 + w;
        if (n < N_NODES) {
            float acc = 0.f;
            #pragma unroll
            for (int qq = 0; qq < 32; ++qq) {
                float4 wv = *(const float4*)&sWn[l * 132 + qq * 4];
                float4 hv = *(const float4*)&sh[w][qq * 4];
                acc += wv.x * hv.x + wv.y * hv.y + wv.z * hv.z + wv.w * hv.w;
            }
            z[(size_t)n * 64 + l] = acc;
            sz[w][l] = acc;
            float p0 = acc * wa0, p1 = acc * wa2;
            #pragma unroll
            for (int off = 32; off; off >>= 1) {
                p0 += __shfl_xor(p0, off);
                p1 += __shfl_xor(p1, off);
            }
            if (l == 0) { asrc[n] = p0; adst[n] = p1; }
        }
        __syncthreads();
        if (n < N_NODES) {
            float acc = 0.f;
            #pragma unroll
            for (int qq = 0; qq < 16; ++qq) {
                float4 wv = *(const float4*)&sW2a[l * 68 + qq * 4];
                float4 zv = *(const float4*)&sz[w][qq * 4];
                acc += wv.x * zv.x + wv.y * zv.y + wv.z * zv.z + wv.w * zv.w;
            }
            y16[(size_t)n * 64 + l] = f2bf(acc);
        }
        __syncthreads();
    }
}

// ---- CSR build ----
__global__ void hist_kernel(const int* __restrict__ dst, int* __restrict__ degi,
                            int* __restrict__ ranks) {
    int e = blockIdx.x * 256 + threadIdx.x;
    if (e < N_EDGES) ranks[e] = atomicAdd(&degi[dst[e]], 1);
}

__global__ __launch_bounds__(256) void scan1_kernel(const int* __restrict__ degi,
                                                    int* __restrict__ partial) {
    int t = threadIdx.x, i = blockIdx.x * 256 + t;
    int d = (i < N_NODES) ? degi[i] : 0;
    #pragma unroll
    for (int off = 32; off; off >>= 1) d += __shfl_down(d, off);
    __shared__ int wsum[4];
    if ((t & 63) == 0) wsum[t >> 6] = d;
    __syncthreads();
    if (t == 0) partial[blockIdx.x] = wsum[0] + wsum[1] + wsum[2] + wsum[3];
}

__global__ __launch_bounds__(256) void scan2_kernel(int* __restrict__ partial) {
    __shared__ int s[256];
    int t = threadIdx.x;
    int v = (t < NB1) ? partial[t] : 0;
    s[t] = v; __syncthreads();
    for (int off = 1; off < 256; off <<= 1) {
        int x = (t >= off) ? s[t - off] : 0;
        __syncthreads();
        s[t] += x;
        __syncthreads();
    }
    if (t < NB1) partial[t] = s[t] - v;   // exclusive, in place
}

__global__ __launch_bounds__(256) void scan3_kernel(const int* __restrict__ degi,
                                                    const int* __restrict__ partial,
                                                    int* __restrict__ start) {
    __shared__ int s[256];
    int t = threadIdx.x, i = blockIdx.x * 256 + t;
    int d = (i < N_NODES) ? degi[i] : 0;
    s[t] = d; __syncthreads();
    for (int off = 1; off < 256; off <<= 1) {
        int x = (t >= off) ? s[t - off] : 0;
        __syncthreads();
        s[t] += x;
        __syncthreads();
    }
    if (i < N_NODES) start[i] = partial[blockIdx.x] + s[t] - d;
}

// ---- Pass A (pipelined): each wave owns 64 edges = 4 batches of 16.
//      Metadata preloaded one-edge-per-lane; batch k+1's edge_feat loads are
//      issued BEFORE batch k's compute/scatter so reads stay in flight. ----
__global__ __launch_bounds__(256) void permute_kernel(
    const float* __restrict__ edge_feat, const int* __restrict__ src,
    const int* __restrict__ dst, const int* __restrict__ ranks,
    const float* __restrict__ asrc, const float* __restrict__ adst,
    const int* __restrict__ start, const float* __restrict__ Wa,
    const short* __restrict__ Bpack, unsigned* __restrict__ gslot)
{
    int t = threadIdx.x, w = t >> 6, l = t & 63;
    int c = l & 15, G = l >> 4;
    int wbase = blockIdx.x * 256 + w * 64;   // grid exact: 3125*256 = 800000

    // B fragments (wave-invariant, 16 VGPRs)
    const bf16x8* Bp = (const bf16x8*)Bpack;
    bf16x8 b00 = Bp[0 * 64 + l];   // s=0,n=0
    bf16x8 b01 = Bp[1 * 64 + l];   // s=0,n=1
    bf16x8 b10 = Bp[2 * 64 + l];   // s=1,n=0
    bf16x8 b11 = Bp[3 * 64 + l];   // s=1,n=1

    // metadata for all 64 edges: one edge per lane (coalesced + L2-resident gathers)
    int e = wbase + l;
    int se = src[e];
    int de = dst[e];
    int slot = start[de] + ranks[e];
    float apre = asrc[se] + adst[de];

    float wam0 = Wa[64 + c], wam1 = Wa[80 + c];

    // prefetch batch 0: lane holds ef[wbase+c][k = 32s + 8G + j]
    const float* efr = edge_feat + (size_t)(wbase + c) * 64 + G * 8;
    float4 n0 = *(const float4*)(efr);
    float4 n1 = *(const float4*)(efr + 4);
    float4 n2 = *(const float4*)(efr + 32);
    float4 n3 = *(const float4*)(efr + 36);

    #pragma unroll
    for (int k = 0; k < 4; ++k) {
        float4 c0 = n0, c1 = n1, c2 = n2, c3 = n3;
        if (k < 3) {   // issue next batch's loads before this batch's compute
            const float* efn = edge_feat + (size_t)(wbase + 16 * (k + 1) + c) * 64 + G * 8;
            n0 = *(const float4*)(efn);
            n1 = *(const float4*)(efn + 4);
            n2 = *(const float4*)(efn + 32);
            n3 = *(const float4*)(efn + 36);
        }
        bf16x8 a0, a1;
        a0[0] = (short)f2bf(c0.x); a0[1] = (short)f2bf(c0.y);
        a0[2] = (short)f2bf(c0.z); a0[3] = (short)f2bf(c0.w);
        a0[4] = (short)f2bf(c1.x); a0[5] = (short)f2bf(c1.y);
        a0[6] = (short)f2bf(c1.z); a0[7] = (short)f2bf(c1.w);
        a1[0] = (short)f2bf(c2.x); a1[1] = (short)f2bf(c2.y);
        a1[2] = (short)f2bf(c2.z); a1[3] = (short)f2bf(c2.w);
        a1[4] = (short)f2bf(c3.x); a1[5] = (short)f2bf(c3.y);
        a1[6] = (short)f2bf(c3.z); a1[7] = (short)f2bf(c3.w);

        f32x4 acc0 = {0.f, 0.f, 0.f, 0.f};
        f32x4 acc1 = {0.f, 0.f, 0.f, 0.f};
        acc0 = __builtin_amdgcn_mfma_f32_16x16x32_bf16(a0, b00, acc0, 0, 0, 0);
        acc0 = __builtin_amdgcn_mfma_f32_16x16x32_bf16(a1, b10, acc0, 0, 0, 0);
        acc1 = __builtin_amdgcn_mfma_f32_16x16x32_bf16(a0, b01, acc1, 0, 0, 0);
        acc1 = __builtin_amdgcn_mfma_f32_16x16x32_bf16(a1, b11, acc1, 0, 0, 0);
        // acc0[r] = g[edge wbase+16k+4G+r][j=c], acc1[r] = g[..][j=16+c]

        #pragma unroll
        for (int r = 0; r < 4; ++r) {
            float p = wam0 * acc0[r] + wam1 * acc1[r];
            p += __shfl_xor(p, 1); p += __shfl_xor(p, 2);
            p += __shfl_xor(p, 4); p += __shfl_xor(p, 8);
            int el = 16 * k + 4 * G + r;
            float a = __shfl(apre, el) + p;
            float sg = a > 0.f ? a : 0.01f * a;
            float ex = __expf(sg);           // segmax shift mathematically redundant
            int sl = __shfl(slot, el);
            int sr = __shfl(se, el);
            gslot[(size_t)sl * 18 + c] = pack2bf(acc0[r], acc1[r]);
            if (c == 0)
                *(int2*)&gslot[(size_t)sl * 18 + 16] = make_int2(__float_as_int(ex), sr);
        }
    }
}

// ---- Pass B: per-node walk; g-slots streamed (CSR order), y16 gathers L2-hot ----
__global__ __launch_bounds__(256) void agg_kernel(
    const unsigned* __restrict__ gslot, const ushort4* __restrict__ y16v,
    const int* __restrict__ start, const int* __restrict__ degi,
    const float* __restrict__ z, const float* __restrict__ W2,
    float* __restrict__ out)
{
    __shared__ float stu[4][164];    // [64:128)=uy, [128:160)=v32 (=We@tm, already projected)
    __shared__ float sW2b[64 * 36];
    int t = threadIdx.x, w = t >> 6, l = t & 63, g = l >> 4, q = l & 15;
    for (int idx = t; idx < 64 * 32; idx += 256)
        sW2b[(idx >> 5) * 36 + (idx & 31)] = W2[(idx >> 5) * 96 + 64 + (idx & 31)];
    __syncthreads();

    int d    = blockIdx.x * 4 + w;           // grid exact: 12500*4 = 50000
    int base = __builtin_amdgcn_readfirstlane(start[d]);
    int deg  = __builtin_amdgcn_readfirstlane(degi[d]);
    float2 tg = make_float2(0.f, 0.f);
    float4 uy4 = make_float4(0.f, 0.f, 0.f, 0.f);
    float den = 0.f;

    for (int c = 0; c < deg; c += 8) {
        int i0 = c + g, i1 = c + 4 + g;
        bool v0 = i0 < deg, v1 = i1 < deg;
        const unsigned* p0 = gslot + (size_t)(base + (v0 ? i0 : 0)) * 18;
        const unsigned* p1 = gslot + (size_t)(base + (v1 ? i1 : 0)) * 18;
        unsigned ga = p0[q], gb = p1[q];
        int2 m0 = *(const int2*)(p0 + 16);
        int2 m1 = *(const int2*)(p1 + 16);
        ushort4 ya = y16v[(size_t)m0.y * 16 + q];
        ushort4 yb = y16v[(size_t)m1.y * 16 + q];
        float ex0 = v0 ? __int_as_float(m0.x) : 0.f;
        float ex1 = v1 ? __int_as_float(m1.x) : 0.f;

        tg.x += ex0 * bf2f((unsigned short)(ga & 0xffffu));
        tg.y += ex0 * bf2f((unsigned short)(ga >> 16));
        uy4.x += ex0 * bf2f(ya.x); uy4.y += ex0 * bf2f(ya.y);
        uy4.z += ex0 * bf2f(ya.z); uy4.w += ex0 * bf2f(ya.w);
        den += ex0;

        tg.x += ex1 * bf2f((unsigned short)(gb & 0xffffu));
        tg.y += ex1 * bf2f((unsigned short)(gb >> 16));
        uy4.x += ex1 * bf2f(yb.x); uy4.y += ex1 * bf2f(yb.y);
        uy4.z += ex1 * bf2f(yb.z); uy4.w += ex1 * bf2f(yb.w);
        den += ex1;
    }

    // combine the 4 edge-slot groups
    tg.x += __shfl_xor(tg.x, 16); tg.x += __shfl_xor(tg.x, 32);
    tg.y += __shfl_xor(tg.y, 16); tg.y += __shfl_xor(tg.y, 32);
    uy4.x += __shfl_xor(uy4.x, 16); uy4.x += __shfl_xor(uy4.x, 32);
    uy4.y += __shfl_xor(uy4.y, 16); uy4.y += __shfl_xor(uy4.y, 32);
    uy4.z += __shfl_xor(uy4.z, 16); uy4.z += __shfl_xor(uy4.z, 32);
    uy4.w += __shfl_xor(uy4.w, 16); uy4.w += __shfl_xor(uy4.w, 32);
    den += __shfl_xor(den, 16); den += __shfl_xor(den, 32);

    if (l < 16) {
        *(float4*)&stu[w][64 + q * 4] = uy4;
        stu[w][128 + q] = tg.x;        // v32[j=q]
        stu[w][144 + q] = tg.y;        // v32[j=16+q]
    }
    // same wave writes+reads stu[w] -> in-order, no barrier needed

    if (deg > 0) {
        float r = 0.f;
        #pragma unroll
        for (int k = 0; k < 8; ++k) {
            float4 wv = *(const float4*)&sW2b[l * 36 + k * 4];
            float4 vv = *(const float4*)&stu[w][128 + k * 4];
            r += wv.x * vv.x + wv.y * vv.y + wv.z * vv.z + wv.w * vv.w;
        }
        out[(size_t)d * 64 + l] = (r + stu[w][64 + l]) / den;
    } else {
        out[(size_t)d * 64 + l] = z[(size_t)d * 64 + l];
    }
}

extern "C" void kernel_launch(void* const* d_in, const int* in_sizes, int n_in,
                              void* d_out, int out_size, void* d_ws, size_t ws_size,
                              hipStream_t stream) {
    const float* h         = (const float*)d_in[0];
    const float* edge_feat = (const float*)d_in[1];
    const int*   src       = (const int*)d_in[2];
    const int*   dst       = (const int*)d_in[3];
    const float* Wn        = (const float*)d_in[4];
    const float* We        = (const float*)d_in[5];
    const float* Wa        = (const float*)d_in[6];
    const float* W2        = (const float*)d_in[7];
    float* out = (float*)d_out;

    char* p = (char*)d_ws;
    float*          z      = (float*)p;          p += (size_t)N_NODES * 64 * 4;   // 12.8 MB
    unsigned short* y16    = (unsigned short*)p; p += (size_t)N_NODES * 64 * 2;   // 6.4 MB
    float*          asrc   = (float*)p;          p += (size_t)N_NODES * 4;
    float*          adst   = (float*)p;          p += (size_t)N_NODES * 4;
    int*            degi   = (int*)p;            p += (size_t)N_NODES * 4;
    int*            start  = (int*)p;            p += (size_t)N_NODES * 4;
    int*            ranks  = (int*)p;            p += (size_t)N_EDGES * 4;        // 3.2 MB
    int*            partial= (int*)p;            p += (size_t)256 * 4;
    short*          Bpack  = (short*)p;          p += (size_t)2048 * 2;           // 4 KB
    unsigned*       gslot  = (unsigned*)p;       p += (size_t)N_EDGES * 18 * 4;   // 57.6 MB

    kw_kernel<<<NB1, 256, 0, stream>>>(We, Bpack, degi);
    node_kernel<<<1024, 256, 0, stream>>>(h, Wn, W2, Wa, z, y16, asrc, adst);
    hist_kernel<<<(N_EDGES + 255) / 256, 256, 0, stream>>>(dst, degi, ranks);
    scan1_kernel<<<NB1, 256, 0, stream>>>(degi, partial);
    scan2_kernel<<<1, 256, 0, stream>>>(partial);
    scan3_kernel<<<NB1, 256, 0, stream>>>(degi, partial, start);
    permute_kernel<<<N_EDGES / 256, 256, 0, stream>>>(edge_feat, src, dst, ranks,
                                                      asrc, adst, start, Wa, Bpack, gslot);
    agg_kernel<<<N_NODES / 4, 256, 0, stream>>>(gslot, (const ushort4*)y16,
                                                start, degi, z, W2, out);
}